// Round 1
// baseline (2688.935 us; speedup 1.0000x reference)
//
#include <hip/hip_runtime.h>

typedef __bf16 bf16x8 __attribute__((ext_vector_type(8)));
typedef __bf16 bf16x4 __attribute__((ext_vector_type(4)));
typedef float  f32x4  __attribute__((ext_vector_type(4)));

#define N_NODES  50000
#define N_EDGES  500000
#define N_GRAPHS 1024
#define NF       128
#define IN_DIM   92
#define N_LAYERS 5

__device__ __forceinline__ float sigmoidf_(float x) { return 1.0f / (1.0f + __expf(-x)); }
__device__ __forceinline__ float softplusf_(float x) {
    // log1p(exp(-|x|)) + max(x, 0)  (stable, matches jax.nn.softplus)
    return log1pf(__expf(-fabsf(x))) + fmaxf(x, 0.0f);
}
__device__ __forceinline__ float siluf_(float x) { return x * sigmoidf_(x); }

// ---------------------------------------------------------------------------
// Weight prep: Wg/Wc fp32 [L][384][128] -> bf16 B-fragment layout with baked
// LDS swizzle. Fragment for mfma_f32_16x16x32_bf16 B operand: lane = sub*16+n,
// holds B[k = s*32 + sub*8 + j][n].  Stored at granule = n*4 + ((sub+(n>>1))&3)
// within each (layer,gate,step) slice of 4096 elems.
// ---------------------------------------------------------------------------
__global__ void __launch_bounds__(256) k_prep_w(const float* __restrict__ Wg,
                                                const float* __restrict__ Wc,
                                                __bf16* __restrict__ Wt) {
    int t = blockIdx.x * 256 + threadIdx.x;
    if (t >= N_LAYERS * 2 * 12 * 128 * 32) return;
    int jj = t & 31;
    int n  = (t >> 5) & 127;
    int s  = (t >> 12) % 12;
    int lg = t / (12 * 4096);
    int l = lg >> 1, g = lg & 1;
    const float* W = g ? Wc : Wg;
    float v = W[l * 384 * 128 + (s * 32 + jj) * 128 + n];
    int sub = jj >> 3, j = jj & 7;
    int gran = n * 4 + ((sub + (n >> 1)) & 3);
    Wt[(size_t)lg * 49152 + (size_t)s * 4096 + gran * 8 + j] = (__bf16)v;
}

// ---------------------------------------------------------------------------
// Atom embedding: h = x @ W_emb + b_emb  (50000x92 @ 92x128)
// ---------------------------------------------------------------------------
__global__ void __launch_bounds__(128) k_embed(const float* __restrict__ x,
                                               const float* __restrict__ W,
                                               const float* __restrict__ b,
                                               float* __restrict__ h,
                                               __bf16* __restrict__ hb) {
    __shared__ float Wl[IN_DIM * NF];
    __shared__ float xs[4][IN_DIM];
    int tid = threadIdx.x;
    for (int i = tid; i < IN_DIM * NF; i += 128) Wl[i] = W[i];
    float bias = b[tid];
    int node0 = blockIdx.x * 64;
    for (int gq = 0; gq < 16; ++gq) {
        int nb = node0 + gq * 4;
        __syncthreads();
        for (int i = tid; i < 4 * IN_DIM; i += 128) {
            int r = i / IN_DIM, k = i - r * IN_DIM;
            int n = nb + r;
            xs[r][k] = (n < N_NODES) ? x[(size_t)n * IN_DIM + k] : 0.0f;
        }
        __syncthreads();
        float a0 = bias, a1 = bias, a2 = bias, a3 = bias;
        #pragma unroll
        for (int k = 0; k < IN_DIM; ++k) {
            float w = Wl[k * NF + tid];
            a0 += xs[0][k] * w; a1 += xs[1][k] * w;
            a2 += xs[2][k] * w; a3 += xs[3][k] * w;
        }
        float accs[4] = {a0, a1, a2, a3};
        #pragma unroll
        for (int r = 0; r < 4; ++r) {
            int n = nb + r;
            if (n < N_NODES) {
                h[(size_t)n * NF + tid]  = accs[r];
                hb[(size_t)n * NF + tid] = (__bf16)accs[r];
            }
        }
    }
}

// ---------------------------------------------------------------------------
// Edge features: RBF(1/d) -> 64 ->silu-> 64  |  sh(9) -> 32 ->silu-> 64
// Output edge_attr bf16 [E][128] = [dist_e(64) | sh_e(64)]
// ---------------------------------------------------------------------------
__global__ void __launch_bounds__(256) k_edge(const float* __restrict__ sh,
    const float* __restrict__ dist,
    const float* __restrict__ shW1, const float* __restrict__ shB1,
    const float* __restrict__ shW2, const float* __restrict__ shB2,
    const float* __restrict__ rbW1, const float* __restrict__ rbB1,
    const float* __restrict__ rbW2, const float* __restrict__ rbB2,
    __bf16* __restrict__ eattr) {
    __shared__ float wf[10752];
    int tid = threadIdx.x;
    for (int i = tid; i < 288;  i += 256) wf[i]         = shW1[i];
    for (int i = tid; i < 32;   i += 256) wf[288 + i]   = shB1[i];
    for (int i = tid; i < 2048; i += 256) wf[320 + i]   = shW2[i];
    for (int i = tid; i < 64;   i += 256) wf[2368 + i]  = shB2[i];
    for (int i = tid; i < 4096; i += 256) wf[2432 + i]  = rbW1[i];
    for (int i = tid; i < 64;   i += 256) wf[6528 + i]  = rbB1[i];
    for (int i = tid; i < 4096; i += 256) wf[6592 + i]  = rbW2[i];
    for (int i = tid; i < 64;   i += 256) wf[10688 + i] = rbB2[i];
    __syncthreads();
    int e = blockIdx.x * 256 + tid;
    if (e >= N_EDGES) return;

    const float* W1 = wf + 2432; const float* B1 = wf + 6528;
    const float* W2 = wf + 6592; const float* B2 = wf + 10688;
    float invd = 1.0f / dist[e];
    const float step = (1.4f - 0.125f) / 63.0f;
    const float gam = 1.0f / (step * step);
    float hid[64];
    #pragma unroll
    for (int j = 0; j < 64; ++j) hid[j] = B1[j];
    for (int i = 0; i < 64; ++i) {
        float c = 0.125f + i * step;
        float d = invd - c;
        float r = __expf(-gam * d * d);
        #pragma unroll
        for (int j = 0; j < 64; ++j) hid[j] += r * W1[i * 64 + j];
    }
    #pragma unroll
    for (int j = 0; j < 64; ++j) hid[j] = siluf_(hid[j]);
    float outv[64];
    #pragma unroll
    for (int o = 0; o < 64; ++o) outv[o] = B2[o];
    for (int j = 0; j < 64; ++j) {
        float hj = hid[j];
        #pragma unroll
        for (int o = 0; o < 64; ++o) outv[o] += hj * W2[j * 64 + o];
    }
    #pragma unroll
    for (int o8 = 0; o8 < 8; ++o8) {
        bf16x8 v;
        #pragma unroll
        for (int j = 0; j < 8; ++j) v[j] = (__bf16)outv[o8 * 8 + j];
        *(bf16x8*)(eattr + (size_t)e * NF + o8 * 8) = v;
    }
    // spherical-harmonics branch
    float shv[9];
    #pragma unroll
    for (int i = 0; i < 9; ++i) shv[i] = sh[(size_t)e * 9 + i];
    const float* sW1 = wf;       const float* sB1 = wf + 288;
    const float* sW2 = wf + 320; const float* sB2 = wf + 2368;
    float h2[32];
    #pragma unroll
    for (int j = 0; j < 32; ++j) h2[j] = sB1[j];
    #pragma unroll
    for (int i = 0; i < 9; ++i) {
        float si = shv[i];
        #pragma unroll
        for (int j = 0; j < 32; ++j) h2[j] += si * sW1[i * 32 + j];
    }
    #pragma unroll
    for (int j = 0; j < 32; ++j) h2[j] = siluf_(h2[j]);
    float o2[64];
    #pragma unroll
    for (int o = 0; o < 64; ++o) o2[o] = sB2[o];
    for (int j = 0; j < 32; ++j) {
        float hj = h2[j];
        #pragma unroll
        for (int o = 0; o < 64; ++o) o2[o] += hj * sW2[j * 64 + o];
    }
    #pragma unroll
    for (int o8 = 0; o8 < 8; ++o8) {
        bf16x8 v;
        #pragma unroll
        for (int j = 0; j < 8; ++j) v[j] = (__bf16)o2[o8 * 8 + j];
        *(bf16x8*)(eattr + (size_t)e * NF + 64 + o8 * 8) = v;
    }
}

// ---------------------------------------------------------------------------
// Message layer: z=[h_dst|h_src|e] (bf16, gathered directly into A-frags),
// m = sigmoid(z@Wg+bg) * softplus(z@Wc+bc), atomicAdd into agg[dst].
// 512 thr = 8 waves, 32 edges/wave (2 M-tiles), N=128 (8 tiles), K=384 (12 steps)
// ---------------------------------------------------------------------------
__global__ void __launch_bounds__(512) k_msg(
    const __bf16* __restrict__ hb, const __bf16* __restrict__ eattr,
    const int* __restrict__ srcI, const int* __restrict__ dstI,
    const __bf16* __restrict__ Wt, const float* __restrict__ bgl,
    const float* __restrict__ bcl, float* __restrict__ agg, int layer)
{
    __shared__ __align__(16) __bf16 lsB[2][2][4096]; // [buf][gate][512 granules x 8]
    int tid = threadIdx.x;
    int lane = tid & 63, wid = tid >> 6;
    int e0 = blockIdx.x * 256 + wid * 32;
    int rA  = lane & 15;
    int sub = lane >> 4;
    int ko  = sub * 8;
    int eA = e0 + rA, eB = e0 + 16 + rA;
    int eAc = min(eA, N_EDGES - 1), eBc = min(eB, N_EDGES - 1);
    const __bf16* pD0 = hb + (size_t)dstI[eAc] * NF + ko;
    const __bf16* pD1 = hb + (size_t)dstI[eBc] * NF + ko;
    const __bf16* pS0 = hb + (size_t)srcI[eAc] * NF + ko;
    const __bf16* pS1 = hb + (size_t)srcI[eBc] * NF + ko;
    const __bf16* pE0 = eattr + (size_t)eAc * NF + ko;
    const __bf16* pE1 = eattr + (size_t)eBc * NF + ko;

    const uint4* gW0 = (const uint4*)(Wt + (size_t)(layer * 2 + 0) * 49152);
    const uint4* gW1 = (const uint4*)(Wt + (size_t)(layer * 2 + 1) * 49152);

    f32x4 accG[2][8], accC[2][8];
    f32x4 zz = {0.f, 0.f, 0.f, 0.f};
    #pragma unroll
    for (int m = 0; m < 2; ++m)
        #pragma unroll
        for (int t = 0; t < 8; ++t) { accG[m][t] = zz; accC[m][t] = zz; }

    // prologue: stage step 0, prefetch A for step 0
    {
        uint4 r0 = gW0[tid], r1 = gW1[tid];
        ((uint4*)&lsB[0][0][0])[tid] = r0;
        ((uint4*)&lsB[0][1][0])[tid] = r1;
    }
    bf16x8 a0 = *(const bf16x8*)pD0;
    bf16x8 a1 = *(const bf16x8*)pD1;
    __syncthreads();

    for (int s = 0; s < 12; ++s) {
        int cur = s & 1, nxt = cur ^ 1;
        bool more = (s < 11);
        uint4 r0, r1;
        bf16x8 na0, na1;
        if (more) {
            r0 = gW0[(s + 1) * 512 + tid];
            r1 = gW1[(s + 1) * 512 + tid];
            int sn = s + 1;
            const __bf16* b0 = (sn < 4) ? pD0 : (sn < 8) ? pS0 : pE0;
            const __bf16* b1 = (sn < 4) ? pD1 : (sn < 8) ? pS1 : pE1;
            int koff = (sn & 3) * 32;
            na0 = *(const bf16x8*)(b0 + koff);
            na1 = *(const bf16x8*)(b1 + koff);
        }
        #pragma unroll
        for (int t = 0; t < 8; ++t) {
            int n = t * 16 + rA;
            int gran = n * 4 + ((sub + (n >> 1)) & 3);
            bf16x8 bgf = *(const bf16x8*)(&lsB[cur][0][gran * 8]);
            bf16x8 bcf = *(const bf16x8*)(&lsB[cur][1][gran * 8]);
            accG[0][t] = __builtin_amdgcn_mfma_f32_16x16x32_bf16(a0, bgf, accG[0][t], 0, 0, 0);
            accG[1][t] = __builtin_amdgcn_mfma_f32_16x16x32_bf16(a1, bgf, accG[1][t], 0, 0, 0);
            accC[0][t] = __builtin_amdgcn_mfma_f32_16x16x32_bf16(a0, bcf, accC[0][t], 0, 0, 0);
            accC[1][t] = __builtin_amdgcn_mfma_f32_16x16x32_bf16(a1, bcf, accC[1][t], 0, 0, 0);
        }
        if (more) {
            ((uint4*)&lsB[nxt][0][0])[tid] = r0;
            ((uint4*)&lsB[nxt][1][0])[tid] = r1;
            a0 = na0; a1 = na1;
        }
        __syncthreads();
    }

    // epilogue: gate + scatter
    int rowbase = sub * 4;
    int dstv[2][4]; bool valid[2][4];
    #pragma unroll
    for (int m = 0; m < 2; ++m)
        #pragma unroll
        for (int r = 0; r < 4; ++r) {
            int e = e0 + m * 16 + rowbase + r;
            valid[m][r] = (e < N_EDGES);
            dstv[m][r] = dstI[min(e, N_EDGES - 1)];
        }
    #pragma unroll
    for (int t = 0; t < 8; ++t) {
        int n = t * 16 + rA;
        float bgn = bgl[n], bcn = bcl[n];
        #pragma unroll
        for (int m = 0; m < 2; ++m) {
            #pragma unroll
            for (int r = 0; r < 4; ++r) {
                float gv = accG[m][t][r] + bgn;
                float cv = accC[m][t][r] + bcn;
                float mv = sigmoidf_(gv) * softplusf_(cv);
                if (valid[m][r]) atomicAdd(&agg[(size_t)dstv[m][r] * NF + n], mv);
            }
        }
    }
}

// ---------------------------------------------------------------------------
// h += agg; hb = bf16(h); agg = 0
// ---------------------------------------------------------------------------
__global__ void __launch_bounds__(256) k_update(float* __restrict__ h,
                                                float* __restrict__ agg,
                                                __bf16* __restrict__ hb) {
    size_t i = (size_t)blockIdx.x * 256 + threadIdx.x;
    float4 hv = ((float4*)h)[i];
    float4 av = ((float4*)agg)[i];
    hv.x += av.x; hv.y += av.y; hv.z += av.z; hv.w += av.w;
    ((float4*)h)[i] = hv;
    ((float4*)agg)[i] = make_float4(0.f, 0.f, 0.f, 0.f);
    bf16x4 o;
    o[0] = (__bf16)hv.x; o[1] = (__bf16)hv.y; o[2] = (__bf16)hv.z; o[3] = (__bf16)hv.w;
    *(bf16x4*)(hb + i * 4) = o;
}

// ---------------------------------------------------------------------------
// Readout: per-graph mean (batch sorted -> binary search), fc 128->128->1
// ---------------------------------------------------------------------------
__global__ void __launch_bounds__(128) k_readout(const float* __restrict__ h,
    const int* __restrict__ batch, const float* __restrict__ W1,
    const float* __restrict__ b1, const float* __restrict__ W2,
    const float* __restrict__ b2, float* __restrict__ out) {
    int g = blockIdx.x, tid = threadIdx.x;
    __shared__ int se[2];
    __shared__ float pl[NF];
    __shared__ float red[2];
    if (tid < 2) {
        int target = g + tid;
        int lo = 0, hi = N_NODES;
        while (lo < hi) { int mid = (lo + hi) >> 1; if (batch[mid] < target) lo = mid + 1; else hi = mid; }
        se[tid] = lo;
    }
    __syncthreads();
    int s = se[0], e = se[1];
    float sum = 0.0f;
    for (int n = s; n < e; ++n) sum += h[(size_t)n * NF + tid];
    float cnt = (float)max(e - s, 1);
    pl[tid] = sum / cnt;
    __syncthreads();
    float acc = b1[tid];
    for (int c = 0; c < NF; ++c) acc += pl[c] * W1[c * NF + tid];
    float hid = siluf_(acc);
    float v = hid * W2[tid];
    #pragma unroll
    for (int off = 32; off > 0; off >>= 1) v += __shfl_down(v, off);
    if ((tid & 63) == 0) red[tid >> 6] = v;
    __syncthreads();
    if (tid == 0) out[g] = red[0] + red[1] + b2[0];
}

// ---------------------------------------------------------------------------
extern "C" void kernel_launch(void* const* d_in, const int* in_sizes, int n_in,
                              void* d_out, int out_size, void* d_ws, size_t ws_size,
                              hipStream_t stream) {
    const float* x     = (const float*)d_in[0];
    const int*   eidx  = (const int*)d_in[1];
    const float* sh    = (const float*)d_in[2];
    const float* edist = (const float*)d_in[3];
    const int*   batch = (const int*)d_in[4];
    const float* W_emb = (const float*)d_in[5];
    const float* b_emb = (const float*)d_in[6];
    const float* shW1  = (const float*)d_in[7];
    const float* shB1  = (const float*)d_in[8];
    const float* shW2  = (const float*)d_in[9];
    const float* shB2  = (const float*)d_in[10];
    const float* rbW1  = (const float*)d_in[11];
    const float* rbB1  = (const float*)d_in[12];
    const float* rbW2  = (const float*)d_in[13];
    const float* rbB2  = (const float*)d_in[14];
    const float* Wg    = (const float*)d_in[15];
    const float* bg    = (const float*)d_in[16];
    const float* Wc    = (const float*)d_in[17];
    const float* bc    = (const float*)d_in[18];
    const float* fcW1  = (const float*)d_in[19];
    const float* fcb1  = (const float*)d_in[20];
    const float* fcW2  = (const float*)d_in[21];
    const float* fcb2  = (const float*)d_in[22];
    const int* srcI = eidx;
    const int* dstI = eidx + N_EDGES;

    char* ws = (char*)d_ws;
    float*  h   = (float*)(ws + 0);            // 25,600,000 B
    __bf16* hb  = (__bf16*)(ws + 25600000);    // 12,800,000 B
    float*  agg = (float*)(ws + 38400000);     // 25,600,000 B
    __bf16* ea  = (__bf16*)(ws + 64000000);    // 128,000,000 B
    __bf16* Wt  = (__bf16*)(ws + 192000000);   //    983,040 B

    hipMemsetAsync(agg, 0, (size_t)N_NODES * NF * sizeof(float), stream);
    k_prep_w<<<1920, 256, 0, stream>>>(Wg, Wc, Wt);
    k_embed<<<(N_NODES + 63) / 64, 128, 0, stream>>>(x, W_emb, b_emb, h, hb);
    k_edge<<<(N_EDGES + 255) / 256, 256, 0, stream>>>(sh, edist, shW1, shB1, shW2, shB2,
                                                      rbW1, rbB1, rbW2, rbB2, ea);
    for (int l = 0; l < N_LAYERS; ++l) {
        k_msg<<<(N_EDGES + 255) / 256, 512, 0, stream>>>(hb, ea, srcI, dstI, Wt,
                                                         bg + l * NF, bc + l * NF, agg, l);
        k_update<<<(N_NODES * NF / 4 + 255) / 256, 256, 0, stream>>>(h, agg, hb);
    }
    k_readout<<<N_GRAPHS, 128, 0, stream>>>(h, batch, fcW1, fcb1, fcW2, fcb2, (float*)d_out);
}